// Round 15
// baseline (117.957 us; speedup 1.0000x reference)
//
#include <hip/hip_runtime.h>
#include <hip/hip_cooperative_groups.h>
#include <cmath>

namespace cg = cooperative_groups;

#define HID 1024
#define OUTN 512
#define VOCABN 1024
#define MSIZE 262144
#define MDIM 128

// workspace layout (floats)
#define WS_TIH 0      // [1024] W_ih@input + b_ih
#define WS_HB  1024   // [1024] hidden_bar
#define WS_H   2048   // [1024] h
#define WS_AW  3072   // [2]    softmax action weights
#define WS_NE  3076   // [128]  new_elt (16B aligned)

typedef float f4_t __attribute__((ext_vector_type(4)));

__device__ __forceinline__ float wred(float v) {
#pragma unroll
    for (int m = 32; m; m >>= 1) v += __shfl_xor(v, m, 64);
    return v;
}

// wave-cooperative dot over n4 float4s (result in all lanes)
__device__ __forceinline__ float dot4(const float4* __restrict__ a,
                                      const float4* __restrict__ b,
                                      int n4, int lane) {
    float acc = 0.f;
    for (int k = lane; k < n4; k += 64) {
        float4 x = a[k], y = b[k];
        acc = fmaf(x.x, y.x, fmaf(x.y, y.y, fmaf(x.z, y.z, fmaf(x.w, y.w, acc))));
    }
    return wred(acc);
}

// Fused chain: phase1 = k_pre, phase2 = k_h, phase3 = k_heads.
// 256 blocks x 256 threads (4 waves/block, row = blockIdx*4 + wave, always
// < 1024 -> no early returns, every thread reaches both grid syncs).
__global__ __launch_bounds__(256) void k_chain(
    const float* __restrict__ input, const float* __restrict__ hidden0,
    const float* __restrict__ stack, const float* __restrict__ W_ih,
    const float* __restrict__ b_ih, const float* __restrict__ W_hh,
    const float* __restrict__ b_hh, const float* __restrict__ W_y,
    const float* __restrict__ b_y, const float* __restrict__ W_n,
    const float* __restrict__ b_n, const float* __restrict__ W_a,
    const float* __restrict__ b_a, const float* __restrict__ W_sh,
    const float* __restrict__ b_sh, float* __restrict__ ws,
    float* __restrict__ d_out) {
    cg::grid_group grid = cg::this_grid();
    const int lane = threadIdx.x & 63;
    const int row  = blockIdx.x * 4 + (threadIdx.x >> 6);  // 0..1023

    // ---- phase 1: t_ih + hidden_bar ----
    {
        const float t  = dot4((const float4*)(W_ih + row * VOCABN),
                              (const float4*)input, VOCABN / 4, lane);
        const float hb = dot4((const float4*)(W_sh + row * MDIM),
                              (const float4*)stack, MDIM / 4, lane);
        if (lane == 0) {
            ws[WS_TIH + row] = t + b_ih[row];
            ws[WS_HB + row]  = hb + b_sh[row] + hidden0[row];
        }
    }
    grid.sync();

    // ---- phase 2: h ----
    {
        const float a = dot4((const float4*)(W_hh + row * HID),
                             (const float4*)(ws + WS_HB), HID / 4, lane);
        if (lane == 0) {
            const float h = tanhf(ws[WS_TIH + row] + a + b_hh[row]);
            ws[WS_H + row] = h;
            d_out[OUTN + row] = h;
        }
    }
    grid.sync();

    // ---- phase 3: heads (rows 0..640 of head work) ----
    {
        const float4* h4 = (const float4*)(ws + WS_H);
        if (row < OUTN) {
            const float a = dot4((const float4*)(W_y + row * HID), h4, HID / 4, lane);
            if (lane == 0) d_out[row] = 1.f / (1.f + expf(-(a + b_y[row])));
        } else if (row < OUTN + MDIM) {
            const int m = row - OUTN;
            const float a = dot4((const float4*)(W_n + m * HID), h4, HID / 4, lane);
            if (lane == 0) ws[WS_NE + m] = 1.f / (1.f + expf(-(a + b_n[m])));
        } else if (row == OUTN + MDIM) {
            float l0 = dot4((const float4*)(W_a), h4, HID / 4, lane);
            float l1 = dot4((const float4*)(W_a + HID), h4, HID / 4, lane);
            if (lane == 0) {
                l0 += b_a[0];
                l1 += b_a[1];
                const float mx = fmaxf(l0, l1);
                const float e0 = expf(l0 - mx), e1 = expf(l1 - mx);
                const float s = e0 + e1;
                ws[WS_AW]     = e0 / s;
                ws[WS_AW + 1] = e1 / s;
            }
        }
    }
}

// Blend: sliding-window + NT stores (R13-exact).
__global__ __launch_bounds__(256, 8) void k_stack(
    const float* __restrict__ stack, const float* __restrict__ ws,
    float* __restrict__ out_stack) {
    const float aw0 = ws[WS_AW];
    const float aw1 = ws[WS_AW + 1];
    const float4* s4  = (const float4*)stack;
    const float4* ne4 = (const float4*)(ws + WS_NE);
    f4_t* o4 = (f4_t*)out_stack;
    const int total4 = MSIZE * (MDIM / 4);              // 8,388,608
    const int lane = threadIdx.x & 63;
    const int wid  = blockIdx.x * 4 + (threadIdx.x >> 6);  // 0..8191
    const long base = (long)wid * 1024;

    float4 prev;
    if (wid == 0) prev = (lane < 32) ? ne4[lane] : s4[lane - 32];
    else          prev = s4[base - 32 + lane];

#pragma unroll 4
    for (int i = 0; i < 16; ++i) {
        const long A = base + i * 64;
        const long nidx = A + 32 + lane;
        float4 next = make_float4(0.f, 0.f, 0.f, 0.f);
        if (nidx < total4) next = s4[nidx];
        f4_t r;
        r.x = fmaf(aw0, prev.x, aw1 * next.x);
        r.y = fmaf(aw0, prev.y, aw1 * next.y);
        r.z = fmaf(aw0, prev.z, aw1 * next.z);
        r.w = fmaf(aw0, prev.w, aw1 * next.w);
        __builtin_nontemporal_store(r, &o4[A + lane]);
        prev = next;
    }
}

extern "C" void kernel_launch(void* const* d_in, const int* in_sizes, int n_in,
                              void* d_out, int out_size, void* d_ws, size_t ws_size,
                              hipStream_t stream) {
    const float* input   = (const float*)d_in[0];
    const float* hidden0 = (const float*)d_in[1];
    const float* stack   = (const float*)d_in[2];
    const float* W_ih    = (const float*)d_in[3];
    const float* W_hh    = (const float*)d_in[4];
    const float* b_ih    = (const float*)d_in[5];
    const float* b_hh    = (const float*)d_in[6];
    const float* W_y     = (const float*)d_in[7];
    const float* b_y     = (const float*)d_in[8];
    const float* W_n     = (const float*)d_in[9];
    const float* b_n     = (const float*)d_in[10];
    const float* W_a     = (const float*)d_in[11];
    const float* b_a     = (const float*)d_in[12];
    const float* W_sh    = (const float*)d_in[13];
    const float* b_sh    = (const float*)d_in[14];
    float* out = (float*)d_out;
    float* ws  = (float*)d_ws;

    void* args[] = {
        (void*)&input, (void*)&hidden0, (void*)&stack, (void*)&W_ih,
        (void*)&b_ih, (void*)&W_hh, (void*)&b_hh, (void*)&W_y,
        (void*)&b_y, (void*)&W_n, (void*)&b_n, (void*)&W_a,
        (void*)&b_a, (void*)&W_sh, (void*)&b_sh, (void*)&ws, (void*)&out,
    };
    hipLaunchCooperativeKernel((void*)k_chain, dim3(256), dim3(256), args, 0, stream);
    k_stack<<<2048, 256, 0, stream>>>(stack, ws, out + OUTN + HID);
}

// Round 16
// 59.681 us; speedup vs baseline: 1.9765x; 1.9765x over previous
//
#include <hip/hip_runtime.h>
#include <cmath>

#define HID 1024
#define OUTN 512
#define VOCABN 1024
#define MSIZE 262144
#define MDIM 128

// workspace layout (floats)
#define WS_TIH 0      // [1024] W_ih@input + b_ih
#define WS_HB  1024   // [1024] hidden_bar
#define WS_H   2048   // [1024] h
#define WS_AW  3072   // [2]    softmax action weights
#define WS_NE  3076   // [128]  new_elt (16B aligned)

typedef float f4_t __attribute__((ext_vector_type(4)));

__device__ __forceinline__ float wred(float v) {
#pragma unroll
    for (int m = 32; m; m >>= 1) v += __shfl_xor(v, m, 64);
    return v;
}

// wave-cooperative dot over n4 float4s (result in all lanes)
__device__ __forceinline__ float dot4(const float4* __restrict__ a,
                                      const float4* __restrict__ b,
                                      int n4, int lane) {
    float acc = 0.f;
    for (int k = lane; k < n4; k += 64) {
        float4 x = a[k], y = b[k];
        acc = fmaf(x.x, y.x, fmaf(x.y, y.y, fmaf(x.z, y.z, fmaf(x.w, y.w, acc))));
    }
    return wred(acc);
}

// Kernel A: t_ih[row] = W_ih[row,:]·input + b_ih[row]
//           hidden_bar[row] = W_sh[row,:]·stack[0,:] + b_sh[row] + hidden0[row]
__global__ void k_pre(const float* __restrict__ input, const float* __restrict__ hidden0,
                      const float* __restrict__ stack, const float* __restrict__ W_ih,
                      const float* __restrict__ b_ih, const float* __restrict__ W_sh,
                      const float* __restrict__ b_sh, float* __restrict__ ws) {
    const int lane = threadIdx.x & 63;
    const int row = blockIdx.x * (blockDim.x >> 6) + (threadIdx.x >> 6);
    if (row >= HID) return;
    float t  = dot4((const float4*)(W_ih + row * VOCABN), (const float4*)input, VOCABN / 4, lane);
    float hb = dot4((const float4*)(W_sh + row * MDIM), (const float4*)stack, MDIM / 4, lane);
    if (lane == 0) {
        ws[WS_TIH + row] = t + b_ih[row];
        ws[WS_HB + row]  = hb + b_sh[row] + hidden0[row];
    }
}

// Kernel B: h[row] = tanh(t_ih[row] + W_hh[row,:]·hidden_bar + b_hh[row])
__global__ void k_h(const float* __restrict__ W_hh, const float* __restrict__ b_hh,
                    float* __restrict__ ws, float* __restrict__ d_out) {
    const int lane = threadIdx.x & 63;
    const int row = blockIdx.x * (blockDim.x >> 6) + (threadIdx.x >> 6);
    if (row >= HID) return;
    float a = dot4((const float4*)(W_hh + row * HID), (const float4*)(ws + WS_HB), HID / 4, lane);
    if (lane == 0) {
        float h = tanhf(ws[WS_TIH + row] + a + b_hh[row]);
        ws[WS_H + row] = h;
        d_out[OUTN + row] = h;
    }
}

// Kernel C: output (512), new_elt (128), action softmax (1 wave)
__global__ void k_heads(const float* __restrict__ W_y, const float* __restrict__ b_y,
                        const float* __restrict__ W_n, const float* __restrict__ b_n,
                        const float* __restrict__ W_a, const float* __restrict__ b_a,
                        float* __restrict__ ws, float* __restrict__ d_out) {
    const int lane = threadIdx.x & 63;
    const int row = blockIdx.x * (blockDim.x >> 6) + (threadIdx.x >> 6);
    const float4* h4 = (const float4*)(ws + WS_H);
    if (row < OUTN) {
        float a = dot4((const float4*)(W_y + row * HID), h4, HID / 4, lane);
        if (lane == 0) d_out[row] = 1.f / (1.f + expf(-(a + b_y[row])));
    } else if (row < OUTN + MDIM) {
        const int m = row - OUTN;
        float a = dot4((const float4*)(W_n + m * HID), h4, HID / 4, lane);
        if (lane == 0) ws[WS_NE + m] = 1.f / (1.f + expf(-(a + b_n[m])));
    } else if (row == OUTN + MDIM) {
        float l0 = dot4((const float4*)(W_a), h4, HID / 4, lane);
        float l1 = dot4((const float4*)(W_a + HID), h4, HID / 4, lane);
        if (lane == 0) {
            l0 += b_a[0];
            l1 += b_a[1];
            const float mx = fmaxf(l0, l1);
            const float e0 = expf(l0 - mx), e1 = expf(l1 - mx);
            const float s = e0 + e1;
            ws[WS_AW]     = e0 / s;
            ws[WS_AW + 1] = e1 / s;
        }
    }
}

// Kernel D: sliding-window blend + NT stores.
// R16 change: 4096 blocks x 8 iters/wave (was 2048 x 16) — halves segment
// size for faster ramp/drain and finer tail balance; full unroll -> 8 loads
// in flight per wave.
__global__ __launch_bounds__(256, 8) void k_stack(
    const float* __restrict__ stack, const float* __restrict__ ws,
    float* __restrict__ out_stack) {
    const float aw0 = ws[WS_AW];
    const float aw1 = ws[WS_AW + 1];
    const float4* s4  = (const float4*)stack;
    const float4* ne4 = (const float4*)(ws + WS_NE);
    f4_t* o4 = (f4_t*)out_stack;
    const int total4 = MSIZE * (MDIM / 4);                 // 8,388,608
    const int lane = threadIdx.x & 63;
    const int wid  = blockIdx.x * 4 + (threadIdx.x >> 6);  // 0..16383
    const long base = (long)wid * 512;

    float4 prev;
    if (wid == 0) prev = (lane < 32) ? ne4[lane] : s4[lane - 32];
    else          prev = s4[base - 32 + lane];

#pragma unroll 8
    for (int i = 0; i < 8; ++i) {
        const long A = base + i * 64;
        const long nidx = A + 32 + lane;
        float4 next = make_float4(0.f, 0.f, 0.f, 0.f);
        if (nidx < total4) next = s4[nidx];
        f4_t r;
        r.x = fmaf(aw0, prev.x, aw1 * next.x);
        r.y = fmaf(aw0, prev.y, aw1 * next.y);
        r.z = fmaf(aw0, prev.z, aw1 * next.z);
        r.w = fmaf(aw0, prev.w, aw1 * next.w);
        __builtin_nontemporal_store(r, &o4[A + lane]);
        prev = next;
    }
}

extern "C" void kernel_launch(void* const* d_in, const int* in_sizes, int n_in,
                              void* d_out, int out_size, void* d_ws, size_t ws_size,
                              hipStream_t stream) {
    const float* input   = (const float*)d_in[0];
    const float* hidden0 = (const float*)d_in[1];
    const float* stack   = (const float*)d_in[2];
    const float* W_ih    = (const float*)d_in[3];
    const float* W_hh    = (const float*)d_in[4];
    const float* b_ih    = (const float*)d_in[5];
    const float* b_hh    = (const float*)d_in[6];
    const float* W_y     = (const float*)d_in[7];
    const float* b_y     = (const float*)d_in[8];
    const float* W_n     = (const float*)d_in[9];
    const float* b_n     = (const float*)d_in[10];
    const float* W_a     = (const float*)d_in[11];
    const float* b_a     = (const float*)d_in[12];
    const float* W_sh    = (const float*)d_in[13];
    const float* b_sh    = (const float*)d_in[14];
    float* out = (float*)d_out;
    float* ws  = (float*)d_ws;

    k_pre<<<256, 256, 0, stream>>>(input, hidden0, stack, W_ih, b_ih, W_sh, b_sh, ws);
    k_h<<<256, 256, 0, stream>>>(W_hh, b_hh, ws, out);
    k_heads<<<161, 256, 0, stream>>>(W_y, b_y, W_n, b_n, W_a, b_a, ws, out);
    k_stack<<<4096, 256, 0, stream>>>(stack, ws, out + OUTN + HID);
}